// Round 13
// baseline (507.756 us; speedup 1.0000x reference)
//
#include <hip/hip_runtime.h>

#define IN_NUM 1152
#define OUT_NUM 10
#define OUT_DIM 16
#define IN_DIM 8
#define NB 256
#define KTOT 9216

#define REP1 8
#define REP2 4
#define REP3 8

// workspace float offsets
#define OFF_SPART 0
#define SZ_SPART (96 * OUT_NUM * OUT_DIM * NB)        // 3,932,160
#define OFF_BP (OFF_SPART + SZ_SPART)
#define SZ_BP (32 * IN_NUM * OUT_NUM)                 // 368,640
#define OFF_VT (OFF_BP + SZ_BP)
#define SZ_VT (NB * OUT_NUM * OUT_DIM)                // 40,960
#define OFF_WT (OFF_VT + SZ_VT)
#define SZ_WT (OUT_NUM * OUT_DIM * KTOT)              // Wt[j][d][k]
#define OFF_WT2 (OFF_WT + SZ_WT)
#define SZ_WT2 (OUT_NUM * KTOT * OUT_DIM)             // Wt2[j][k][d]
#define OFF_XT (OFF_WT2 + SZ_WT2)
#define SZ_XT (KTOT * NB)                             // xT[k][b]

// ---- prep: xT[k][b] = x[b][k];  Wt[j][d*8+c][i], Wt2[j][c*1152+i][d] = W[i][j][d][c] ----
__global__ __launch_bounds__(256) void k_prep(const float* __restrict__ x,
                                              const float* __restrict__ W,
                                              float* __restrict__ xT,
                                              float* __restrict__ Wt,
                                              float* __restrict__ Wt2) {
    __shared__ float smem[64 * 68];
    int u = blockIdx.x, t = threadIdx.x;
    if (u < 576) {
        float (*lds)[68] = (float (*)[68])smem;
        int kt = u % 144, bt = u / 144;
        int k0 = kt * 64, b0 = bt * 64;
        int r = t >> 4, c4 = (t & 15) * 4;
#pragma unroll
        for (int p = 0; p < 4; ++p) {
            int bb = p * 16 + r;
            float4 v = *reinterpret_cast<const float4*>(&x[(size_t)(b0 + bb) * KTOT + k0 + c4]);
            lds[bb][c4 + 0] = v.x; lds[bb][c4 + 1] = v.y;
            lds[bb][c4 + 2] = v.z; lds[bb][c4 + 3] = v.w;
        }
        __syncthreads();
#pragma unroll
        for (int p = 0; p < 4; ++p) {
            int kk = p * 16 + r;
            float4 o;
            o.x = lds[c4 + 0][kk]; o.y = lds[c4 + 1][kk];
            o.z = lds[c4 + 2][kk]; o.w = lds[c4 + 3][kk];
            *reinterpret_cast<float4*>(&xT[(size_t)(k0 + kk) * NB + b0 + c4]) = o;
        }
    } else {
        float (*lds2)[129] = (float (*)[129])smem;
        int w = u - 576;
        int itile = w / 10, j = w - itile * 10;
        int i0 = itile * 32;
        int r0 = t >> 5, c4b = t & 31;
#pragma unroll
        for (int rr = 0; rr < 4; ++rr) {
            int rrow = rr * 8 + r0;
            float4 w4 = *reinterpret_cast<const float4*>(
                &W[(size_t)(i0 + rrow) * 1280 + j * 128 + c4b * 4]);
            lds2[rrow][c4b * 4 + 0] = w4.x; lds2[rrow][c4b * 4 + 1] = w4.y;
            lds2[rrow][c4b * 4 + 2] = w4.z; lds2[rrow][c4b * 4 + 3] = w4.w;
        }
        __syncthreads();
        int ii = t & 31, dcq = t >> 5;
#pragma unroll
        for (int rr = 0; rr < 16; ++rr) {
            int dc = rr * 8 + dcq;
            Wt[(size_t)(j * 128 + dc) * IN_NUM + i0 + ii] = lds2[ii][dc];
        }
        int d4 = t & 3, ii2 = (t >> 2) & 31, ch0 = t >> 7;
#pragma unroll
        for (int c2 = 0; c2 < 4; ++c2) {
            int c = c2 * 2 + ch0;
            float4 o;
            o.x = lds2[ii2][(d4 * 4 + 0) * 8 + c];
            o.y = lds2[ii2][(d4 * 4 + 1) * 8 + c];
            o.z = lds2[ii2][(d4 * 4 + 2) * 8 + c];
            o.w = lds2[ii2][(d4 * 4 + 3) * 8 + c];
            *reinterpret_cast<float4*>(
                &Wt2[((size_t)j * KTOT + c * IN_NUM + i0 + ii2) * OUT_DIM + d4 * 4]) = o;
        }
    }
}

// ---- p1 (DIAGNOSTIC x REP1): spart[isp][j][d][b] = sum_kk (ldc[kk]*Wt2[j][k][d]) * xT[k][b] ----
__global__ __launch_bounds__(256, 4) void k_p1(const float* __restrict__ xT,
                                               const float* __restrict__ Wt2,
                                               const float* __restrict__ bp,
                                               float* __restrict__ spart, int it) {
    __shared__ float ldc[96];
    int w = blockIdx.x, t = threadIdx.x;
    int g8 = w / 80, r = w - g8 * 80;
    int j = r >> 3, isp = g8 * 8 + (r & 7);
    int cch = isp / 12;
    int i0 = (isp - cch * 12) * 96;
    int k0 = isp * 96;
    if (t < 96) {
        float cv;
        if (it == 0) {
            cv = 0.1f;
        } else {
            int i = i0 + t;
            float bt_[OUT_NUM];
#pragma unroll
            for (int jp = 0; jp < OUT_NUM; ++jp) bt_[jp] = 0.f;
#pragma unroll 4
            for (int row = 0; row < 32; ++row) {
                const float2* p2 = reinterpret_cast<const float2*>(
                    &bp[(size_t)row * (IN_NUM * OUT_NUM) + i * OUT_NUM]);
#pragma unroll
                for (int q = 0; q < 5; ++q) {
                    float2 v = p2[q];
                    bt_[q * 2] += v.x; bt_[q * 2 + 1] += v.y;
                }
            }
            float m = -1e30f;
#pragma unroll
            for (int jp = 0; jp < OUT_NUM; ++jp) { bt_[jp] *= (1.f / NB); m = fmaxf(m, bt_[jp]); }
            float s = 0.f;
#pragma unroll
            for (int jp = 0; jp < OUT_NUM; ++jp) { bt_[jp] = __expf(bt_[jp] - m); s += bt_[jp]; }
            cv = bt_[j] / s;
        }
        ldc[t] = cv;
    }
    __syncthreads();
    const float* xp = xT + (size_t)k0 * NB + t;
    const float* wp = Wt2 + ((size_t)j * KTOT + k0) * OUT_DIM;
    float acc[16];
    for (int rep = 0; rep < REP1; ++rep) {
        asm volatile("" ::: "memory");   // force reloads; no cross-rep CSE/hoist
#pragma unroll
        for (int d = 0; d < 16; ++d) acc[d] = 0.f;
#pragma unroll 4
        for (int kk = 0; kk < 96; ++kk) {
            float xv = xp[(size_t)kk * NB];
            float xs = xv * ldc[kk];
            const float* a = wp + kk * OUT_DIM;
#pragma unroll
            for (int d = 0; d < 16; ++d) acc[d] += a[d] * xs;
        }
#pragma unroll
        for (int d = 0; d < 16; ++d) asm volatile("" :: "v"(acc[d]));   // keep each rep live
    }
    float* sp = spart + ((size_t)isp * OUT_NUM + j) * (OUT_DIM * NB) + t;
#pragma unroll
    for (int d = 0; d < 16; ++d) sp[d * NB] = acc[d];
}

// ---- p2 (DIAGNOSTIC x REP2): reduce spart over isp, squash, write dst[b][j][d] ----
__global__ __launch_bounds__(256, 4) void k_p2(const float* __restrict__ spart,
                                               float* __restrict__ dst) {
    __shared__ float smem[4672];
    float (*red)[32][17] = (float (*)[32][17])smem;
    float (*nrm)[9] = (float (*)[9])(smem + 4352);
    float* cf = smem + 4640;
    int wvar = blockIdx.x, t = threadIdx.x;
    int j = wvar >> 3, bt2 = wvar & 7;
    int ie = t >> 5, bb = t & 31;
    int b = bt2 * 32 + bb;
    float acc[16];
    for (int rep = 0; rep < REP2; ++rep) {
        asm volatile("" ::: "memory");
#pragma unroll
        for (int d = 0; d < 16; ++d) acc[d] = 0.f;
        for (int q = 0; q < 12; ++q) {
            int isp = ie * 12 + q;
            const float* sp = spart + (size_t)(isp * OUT_NUM + j) * (OUT_DIM * NB) + b;
#pragma unroll
            for (int d = 0; d < 16; ++d) acc[d] += sp[d * NB];
        }
#pragma unroll
        for (int d = 0; d < 16; ++d) asm volatile("" :: "v"(acc[d]));
    }
#pragma unroll
    for (int d = 0; d < 16; ++d) red[ie][bb][d] = acc[d];
    __syncthreads();
    int bb2 = t >> 3, dp = t & 7;
    float s0 = 0.f, s1 = 0.f;
#pragma unroll
    for (int e = 0; e < 8; ++e) { s0 += red[e][bb2][dp * 2]; s1 += red[e][bb2][dp * 2 + 1]; }
    nrm[bb2][dp] = s0 * s0 + s1 * s1;
    __syncthreads();
    if (t < 32) {
        float qn = 0.f;
#pragma unroll
        for (int d = 0; d < 8; ++d) qn += nrm[t][d];
        cf[t] = qn / ((1.f + qn) * sqrtf(qn));
    }
    __syncthreads();
    float cs = cf[bb2];
    float* o = dst + (size_t)(bt2 * 32 + bb2) * (OUT_NUM * OUT_DIM) + j * OUT_DIM + dp * 2;
    o[0] = s0 * cs;
    o[1] = s1 * cs;
}

// ---- p3 (DIAGNOSTIC x REP3): bp update (R11/R6 validated form) ----
__global__ __launch_bounds__(256) void k_p3(const float* __restrict__ x,
                                            const float* __restrict__ vt,
                                            const float* __restrict__ Wt,
                                            float* __restrict__ bp, int it) {
    int u = blockIdx.x, t = threadIdx.x;
    int kt = u % 36;
    int jq = u / 36;
    int j = jq >> 2, bq = jq & 3;
    int k = kt * 256 + t;
    int c = k / IN_NUM, i = k - c * IN_NUM;
    const float* xk = x + k + (size_t)(bq * 64) * KTOT;
    const float* vjb = vt + (size_t)(bq * 64) * (OUT_NUM * OUT_DIM) + j * OUT_DIM;
    float bs = 0.f;
    for (int rep = 0; rep < REP3; ++rep) {
        asm volatile("" ::: "memory");
        float macc[16];
#pragma unroll
        for (int d = 0; d < 16; ++d) macc[d] = 0.f;
#pragma unroll 8
        for (int b = 0; b < 64; ++b) {
            float xv = xk[(size_t)b * KTOT];
            const float* vb = vjb + (size_t)b * (OUT_NUM * OUT_DIM);
#pragma unroll
            for (int d = 0; d < 16; ++d) macc[d] += vb[d] * xv;
        }
        bs = 0.f;
#pragma unroll
        for (int d = 0; d < 16; ++d)
            bs += macc[d] * Wt[(size_t)(j * OUT_DIM + d) * KTOT + k];
        asm volatile("" :: "v"(bs));
    }
    size_t idx = (size_t)(bq * 8 + c) * (IN_NUM * OUT_NUM) + (size_t)i * OUT_NUM + j;
    float prev = (it == 0) ? 0.f : bp[idx];
    bp[idx] = prev + bs;
}

extern "C" void kernel_launch(void* const* d_in, const int* in_sizes, int n_in,
                              void* d_out, int out_size, void* d_ws, size_t ws_size,
                              hipStream_t stream) {
    const float* x = (const float*)d_in[0];   // [256][8][1152]
    const float* W = (const float*)d_in[1];   // [1152][10][16][8]
    float* out = (float*)d_out;               // [256][10][16][1]
    float* ws = (float*)d_ws;

    float* spart = ws + OFF_SPART;
    float* bp    = ws + OFF_BP;
    float* vt    = ws + OFF_VT;
    float* Wt    = ws + OFF_WT;
    float* Wt2   = ws + OFF_WT2;
    float* xT    = ws + OFF_XT;

    k_prep<<<dim3(936), dim3(256), 0, stream>>>(x, W, xT, Wt, Wt2);
    for (int it = 0; it < 3; ++it) {
        k_p1<<<dim3(960), dim3(256), 0, stream>>>(xT, Wt2, bp, spart, it);
        k_p2<<<dim3(80), dim3(256), 0, stream>>>(spart, it == 2 ? out : vt);
        if (it < 2) k_p3<<<dim3(1440), dim3(256), 0, stream>>>(x, vt, Wt, bp, it);
    }
}

// Round 14
// 185.564 us; speedup vs baseline: 2.7363x; 2.7363x over previous
//
#include <hip/hip_runtime.h>

#define IN_NUM 1152
#define OUT_NUM 10
#define OUT_DIM 16
#define IN_DIM 8
#define NB 256
#define KTOT 9216

// workspace float offsets
#define OFF_SPART 0
#define SZ_SPART (96 * OUT_NUM * OUT_DIM * NB)        // 3,932,160
#define OFF_BP (OFF_SPART + SZ_SPART)
#define SZ_BP (32 * IN_NUM * OUT_NUM)                 // 368,640
#define OFF_VT (OFF_BP + SZ_BP)
#define SZ_VT (NB * OUT_NUM * OUT_DIM)                // 40,960
#define OFF_WT (OFF_VT + SZ_VT)
#define SZ_WT (OUT_NUM * OUT_DIM * KTOT)              // Wt[j][d][k]
#define OFF_WT2 (OFF_WT + SZ_WT)
#define SZ_WT2 (OUT_NUM * KTOT * OUT_DIM)             // Wt2[j][k][d]
#define OFF_XT (OFF_WT2 + SZ_WT2)
#define SZ_XT (KTOT * NB)                             // xT[k][b]

// ---- prep: xT[k][b] = x[b][k];  Wt[j][d*8+c][i], Wt2[j][c*1152+i][d] = W[i][j][d][c] ----
__global__ __launch_bounds__(256) void k_prep(const float* __restrict__ x,
                                              const float* __restrict__ W,
                                              float* __restrict__ xT,
                                              float* __restrict__ Wt,
                                              float* __restrict__ Wt2) {
    __shared__ float smem[64 * 68];
    int u = blockIdx.x, t = threadIdx.x;
    if (u < 576) {
        float (*lds)[68] = (float (*)[68])smem;
        int kt = u % 144, bt = u / 144;
        int k0 = kt * 64, b0 = bt * 64;
        int r = t >> 4, c4 = (t & 15) * 4;
#pragma unroll
        for (int p = 0; p < 4; ++p) {
            int bb = p * 16 + r;
            float4 v = *reinterpret_cast<const float4*>(&x[(size_t)(b0 + bb) * KTOT + k0 + c4]);
            lds[bb][c4 + 0] = v.x; lds[bb][c4 + 1] = v.y;
            lds[bb][c4 + 2] = v.z; lds[bb][c4 + 3] = v.w;
        }
        __syncthreads();
#pragma unroll
        for (int p = 0; p < 4; ++p) {
            int kk = p * 16 + r;
            float4 o;
            o.x = lds[c4 + 0][kk]; o.y = lds[c4 + 1][kk];
            o.z = lds[c4 + 2][kk]; o.w = lds[c4 + 3][kk];
            *reinterpret_cast<float4*>(&xT[(size_t)(k0 + kk) * NB + b0 + c4]) = o;
        }
    } else {
        float (*lds2)[129] = (float (*)[129])smem;
        int w = u - 576;
        int itile = w / 10, j = w - itile * 10;
        int i0 = itile * 32;
        int r0 = t >> 5, c4b = t & 31;
#pragma unroll
        for (int rr = 0; rr < 4; ++rr) {
            int rrow = rr * 8 + r0;
            float4 w4 = *reinterpret_cast<const float4*>(
                &W[(size_t)(i0 + rrow) * 1280 + j * 128 + c4b * 4]);
            lds2[rrow][c4b * 4 + 0] = w4.x; lds2[rrow][c4b * 4 + 1] = w4.y;
            lds2[rrow][c4b * 4 + 2] = w4.z; lds2[rrow][c4b * 4 + 3] = w4.w;
        }
        __syncthreads();
        int ii = t & 31, dcq = t >> 5;
#pragma unroll
        for (int rr = 0; rr < 16; ++rr) {
            int dc = rr * 8 + dcq;
            Wt[(size_t)(j * 128 + dc) * IN_NUM + i0 + ii] = lds2[ii][dc];
        }
        int d4 = t & 3, ii2 = (t >> 2) & 31, ch0 = t >> 7;
#pragma unroll
        for (int c2 = 0; c2 < 4; ++c2) {
            int c = c2 * 2 + ch0;
            float4 o;
            o.x = lds2[ii2][(d4 * 4 + 0) * 8 + c];
            o.y = lds2[ii2][(d4 * 4 + 1) * 8 + c];
            o.z = lds2[ii2][(d4 * 4 + 2) * 8 + c];
            o.w = lds2[ii2][(d4 * 4 + 3) * 8 + c];
            *reinterpret_cast<float4*>(
                &Wt2[((size_t)j * KTOT + c * IN_NUM + i0 + ii2) * OUT_DIM + d4 * 4]) = o;
        }
    }
}

// ---- p1: j-PAIR per block. spart[isp][j][d][b] = sum_kk (ldc[j][kk]*Wt2[j][k][d]) * xT[k][b] ----
// 480 blocks: bid = g*40 + jp*8 + e; isp = g*8+e (stride-8 -> jp-blocks sharing isp on one XCD).
__global__ __launch_bounds__(256, 4) void k_p1(const float* __restrict__ xT,
                                               const float* __restrict__ Wt2,
                                               const float* __restrict__ bp,
                                               float* __restrict__ spart, int it) {
    __shared__ float ldc[2][96];
    int bid = blockIdx.x, t = threadIdx.x;
    int g = bid / 40, r = bid - g * 40;
    int jp = r >> 3, e = r & 7;
    int isp = g * 8 + e;
    int j0 = jp * 2;
    int cch = isp / 12;
    int i0 = (isp - cch * 12) * 96;
    int k0 = isp * 96;
    if (t < 96) {
        if (it == 0) {
            ldc[0][t] = 0.1f;
            ldc[1][t] = 0.1f;
        } else {
            int i = i0 + t;
            float bt_[OUT_NUM];
#pragma unroll
            for (int jq = 0; jq < OUT_NUM; ++jq) bt_[jq] = 0.f;
#pragma unroll 4
            for (int row = 0; row < 32; ++row) {
                const float2* p2 = reinterpret_cast<const float2*>(
                    &bp[(size_t)row * (IN_NUM * OUT_NUM) + i * OUT_NUM]);
#pragma unroll
                for (int q = 0; q < 5; ++q) {
                    float2 v = p2[q];
                    bt_[q * 2] += v.x; bt_[q * 2 + 1] += v.y;
                }
            }
            float m = -1e30f;
#pragma unroll
            for (int jq = 0; jq < OUT_NUM; ++jq) { bt_[jq] *= (1.f / NB); m = fmaxf(m, bt_[jq]); }
            float s = 0.f;
#pragma unroll
            for (int jq = 0; jq < OUT_NUM; ++jq) { bt_[jq] = __expf(bt_[jq] - m); s += bt_[jq]; }
            float inv = 1.0f / s;
            ldc[0][t] = bt_[j0] * inv;
            ldc[1][t] = bt_[j0 + 1] * inv;
        }
    }
    __syncthreads();
    const float* xp = xT + (size_t)k0 * NB + t;
    const float* wp0 = Wt2 + ((size_t)j0 * KTOT + k0) * OUT_DIM;        // block-uniform
    const float* wp1 = Wt2 + ((size_t)(j0 + 1) * KTOT + k0) * OUT_DIM;  // block-uniform
    float a0[16], a1[16];
#pragma unroll
    for (int d = 0; d < 16; ++d) { a0[d] = 0.f; a1[d] = 0.f; }
#pragma unroll 4
    for (int kk = 0; kk < 96; ++kk) {
        float xv = xp[(size_t)kk * NB];
        float xs0 = xv * ldc[0][kk];
        float xs1 = xv * ldc[1][kk];
        const float* w0 = wp0 + kk * OUT_DIM;
        const float* w1 = wp1 + kk * OUT_DIM;
#pragma unroll
        for (int d = 0; d < 16; ++d) a0[d] += w0[d] * xs0;
#pragma unroll
        for (int d = 0; d < 16; ++d) a1[d] += w1[d] * xs1;
    }
    float* sp0 = spart + ((size_t)isp * OUT_NUM + j0) * (OUT_DIM * NB) + t;
    float* sp1 = sp0 + (size_t)OUT_DIM * NB;
#pragma unroll
    for (int d = 0; d < 16; ++d) sp0[d * NB] = a0[d];
#pragma unroll
    for (int d = 0; d < 16; ++d) sp1[d * NB] = a1[d];
}

// ---- p2: reduce spart over isp, squash, write dst[b][j][d] ----
__global__ __launch_bounds__(256, 4) void k_p2(const float* __restrict__ spart,
                                               float* __restrict__ dst) {
    __shared__ float smem[4672];
    float (*red)[32][17] = (float (*)[32][17])smem;
    float (*nrm)[9] = (float (*)[9])(smem + 4352);
    float* cf = smem + 4640;
    int wvar = blockIdx.x, t = threadIdx.x;
    int j = wvar >> 3, bt2 = wvar & 7;
    int ie = t >> 5, bb = t & 31;
    int b = bt2 * 32 + bb;
    float acc[16];
#pragma unroll
    for (int d = 0; d < 16; ++d) acc[d] = 0.f;
    for (int q = 0; q < 12; ++q) {
        int isp = ie * 12 + q;
        const float* sp = spart + (size_t)(isp * OUT_NUM + j) * (OUT_DIM * NB) + b;
#pragma unroll
        for (int d = 0; d < 16; ++d) acc[d] += sp[d * NB];
    }
#pragma unroll
    for (int d = 0; d < 16; ++d) red[ie][bb][d] = acc[d];
    __syncthreads();
    int bb2 = t >> 3, dp = t & 7;
    float s0 = 0.f, s1 = 0.f;
#pragma unroll
    for (int e = 0; e < 8; ++e) { s0 += red[e][bb2][dp * 2]; s1 += red[e][bb2][dp * 2 + 1]; }
    nrm[bb2][dp] = s0 * s0 + s1 * s1;
    __syncthreads();
    if (t < 32) {
        float qn = 0.f;
#pragma unroll
        for (int d = 0; d < 8; ++d) qn += nrm[t][d];
        cf[t] = qn / ((1.f + qn) * sqrtf(qn));
    }
    __syncthreads();
    float cs = cf[bb2];
    float* o = dst + (size_t)(bt2 * 32 + bb2) * (OUT_NUM * OUT_DIM) + j * OUT_DIM + dp * 2;
    o[0] = s0 * cs;
    o[1] = s1 * cs;
}

// ---- p3: j-PAIR per block. bp[bq*8+c][i][j0:j0+2] update ----
// 720 blocks: bid = q*40 + jp*8 + e; m = q*8+e -> (kt,bq). Blocks sharing the x-slice
// (same kt,bq; 5 jp's) sit stride-8 apart -> same XCD (L2 reuse).
__global__ __launch_bounds__(256) void k_p3(const float* __restrict__ x,
                                            const float* __restrict__ vt,
                                            const float* __restrict__ Wt,
                                            float* __restrict__ bp, int it) {
    int bid = blockIdx.x, t = threadIdx.x;
    int q = bid / 40, r = bid - q * 40;
    int jp = r >> 3, e = r & 7;
    int m = q * 8 + e;           // 0..143
    int kt = m >> 2, bq = m & 3; // 36 k-tiles x 4 b-quarters
    int j0 = jp * 2;
    int k = kt * 256 + t;
    int c = k / IN_NUM, i = k - c * IN_NUM;
    const float* xk = x + k + (size_t)(bq * 64) * KTOT;
    const float* vjb0 = vt + (size_t)(bq * 64) * (OUT_NUM * OUT_DIM) + j0 * OUT_DIM;
    float m0[16], m1[16];
#pragma unroll
    for (int d = 0; d < 16; ++d) { m0[d] = 0.f; m1[d] = 0.f; }
#pragma unroll 4
    for (int b = 0; b < 64; ++b) {
        float xv = xk[(size_t)b * KTOT];
        const float* vb = vjb0 + (size_t)b * (OUT_NUM * OUT_DIM);   // block-uniform -> s_load x32
#pragma unroll
        for (int d = 0; d < 16; ++d) m0[d] += vb[d] * xv;
#pragma unroll
        for (int d = 0; d < 16; ++d) m1[d] += vb[16 + d] * xv;
    }
    float bs0 = 0.f, bs1 = 0.f;
#pragma unroll
    for (int d = 0; d < 16; ++d) {
        bs0 += m0[d] * Wt[(size_t)(j0 * OUT_DIM + d) * KTOT + k];
        bs1 += m1[d] * Wt[(size_t)((j0 + 1) * OUT_DIM + d) * KTOT + k];
    }
    size_t idx = (size_t)(bq * 8 + c) * (IN_NUM * OUT_NUM) + (size_t)i * OUT_NUM + j0;
    float2* bp2 = reinterpret_cast<float2*>(&bp[idx]);   // j0 even -> 8B aligned
    float2 prev = (it == 0) ? make_float2(0.f, 0.f) : *bp2;
    *bp2 = make_float2(prev.x + bs0, prev.y + bs1);
}

extern "C" void kernel_launch(void* const* d_in, const int* in_sizes, int n_in,
                              void* d_out, int out_size, void* d_ws, size_t ws_size,
                              hipStream_t stream) {
    const float* x = (const float*)d_in[0];   // [256][8][1152]
    const float* W = (const float*)d_in[1];   // [1152][10][16][8]
    float* out = (float*)d_out;               // [256][10][16][1]
    float* ws = (float*)d_ws;

    float* spart = ws + OFF_SPART;
    float* bp    = ws + OFF_BP;
    float* vt    = ws + OFF_VT;
    float* Wt    = ws + OFF_WT;
    float* Wt2   = ws + OFF_WT2;
    float* xT    = ws + OFF_XT;

    k_prep<<<dim3(936), dim3(256), 0, stream>>>(x, W, xT, Wt, Wt2);
    for (int it = 0; it < 3; ++it) {
        k_p1<<<dim3(480), dim3(256), 0, stream>>>(xT, Wt2, bp, spart, it);
        k_p2<<<dim3(80), dim3(256), 0, stream>>>(spart, it == 2 ? out : vt);
        if (it < 2) k_p3<<<dim3(720), dim3(256), 0, stream>>>(x, vt, Wt, bp, it);
    }
}

// Round 15
// 123.416 us; speedup vs baseline: 4.1142x; 1.5036x over previous
//
#include <hip/hip_runtime.h>

#define IN_NUM 1152
#define OUT_NUM 10
#define OUT_DIM 16
#define IN_DIM 8
#define NB 256
#define KTOT 9216

// workspace float offsets
#define OFF_SPART 0
#define SZ_SPART (96 * OUT_NUM * OUT_DIM * NB)        // 3,932,160
#define OFF_BP (OFF_SPART + SZ_SPART)
#define SZ_BP (32 * IN_NUM * OUT_NUM)                 // 368,640
#define OFF_VT (OFF_BP + SZ_BP)
#define SZ_VT (NB * OUT_NUM * OUT_DIM)                // 40,960
#define OFF_WT (OFF_VT + SZ_VT)
#define SZ_WT (OUT_NUM * OUT_DIM * KTOT)              // Wt[j][d][k]
#define OFF_WT2 (OFF_WT + SZ_WT)
#define SZ_WT2 (OUT_NUM * KTOT * OUT_DIM)             // Wt2[j][k][d]
#define OFF_XT (OFF_WT2 + SZ_WT2)
#define SZ_XT (KTOT * NB)                             // xT[k][b]

// ---- prep: xT[k][b] = x[b][k];  Wt[j][d*8+c][i], Wt2[j][c*1152+i][d] = W[i][j][d][c] ----
__global__ __launch_bounds__(256) void k_prep(const float* __restrict__ x,
                                              const float* __restrict__ W,
                                              float* __restrict__ xT,
                                              float* __restrict__ Wt,
                                              float* __restrict__ Wt2) {
    __shared__ float smem[64 * 68];
    int u = blockIdx.x, t = threadIdx.x;
    if (u < 576) {
        float (*lds)[68] = (float (*)[68])smem;
        int kt = u % 144, bt = u / 144;
        int k0 = kt * 64, b0 = bt * 64;
        int r = t >> 4, c4 = (t & 15) * 4;
#pragma unroll
        for (int p = 0; p < 4; ++p) {
            int bb = p * 16 + r;
            float4 v = *reinterpret_cast<const float4*>(&x[(size_t)(b0 + bb) * KTOT + k0 + c4]);
            lds[bb][c4 + 0] = v.x; lds[bb][c4 + 1] = v.y;
            lds[bb][c4 + 2] = v.z; lds[bb][c4 + 3] = v.w;
        }
        __syncthreads();
#pragma unroll
        for (int p = 0; p < 4; ++p) {
            int kk = p * 16 + r;
            float4 o;
            o.x = lds[c4 + 0][kk]; o.y = lds[c4 + 1][kk];
            o.z = lds[c4 + 2][kk]; o.w = lds[c4 + 3][kk];
            *reinterpret_cast<float4*>(&xT[(size_t)(k0 + kk) * NB + b0 + c4]) = o;
        }
    } else {
        float (*lds2)[129] = (float (*)[129])smem;
        int w = u - 576;
        int itile = w / 10, j = w - itile * 10;
        int i0 = itile * 32;
        int r0 = t >> 5, c4b = t & 31;
#pragma unroll
        for (int rr = 0; rr < 4; ++rr) {
            int rrow = rr * 8 + r0;
            float4 w4 = *reinterpret_cast<const float4*>(
                &W[(size_t)(i0 + rrow) * 1280 + j * 128 + c4b * 4]);
            lds2[rrow][c4b * 4 + 0] = w4.x; lds2[rrow][c4b * 4 + 1] = w4.y;
            lds2[rrow][c4b * 4 + 2] = w4.z; lds2[rrow][c4b * 4 + 3] = w4.w;
        }
        __syncthreads();
        int ii = t & 31, dcq = t >> 5;
#pragma unroll
        for (int rr = 0; rr < 16; ++rr) {
            int dc = rr * 8 + dcq;
            Wt[(size_t)(j * 128 + dc) * IN_NUM + i0 + ii] = lds2[ii][dc];
        }
        int d4 = t & 3, ii2 = (t >> 2) & 31, ch0 = t >> 7;
#pragma unroll
        for (int c2 = 0; c2 < 4; ++c2) {
            int c = c2 * 2 + ch0;
            float4 o;
            o.x = lds2[ii2][(d4 * 4 + 0) * 8 + c];
            o.y = lds2[ii2][(d4 * 4 + 1) * 8 + c];
            o.z = lds2[ii2][(d4 * 4 + 2) * 8 + c];
            o.w = lds2[ii2][(d4 * 4 + 3) * 8 + c];
            *reinterpret_cast<float4*>(
                &Wt2[((size_t)j * KTOT + c * IN_NUM + i0 + ii2) * OUT_DIM + d4 * 4]) = o;
        }
    }
}

// ---- p1: spart[isp][j][d][b] = sum_kk (ldc[kk]*Wt2[j][k][d]) * xT[k][b] ----
__global__ __launch_bounds__(256, 4) void k_p1(const float* __restrict__ xT,
                                               const float* __restrict__ Wt2,
                                               const float* __restrict__ bp,
                                               float* __restrict__ spart, int it) {
    __shared__ float ldc[96];
    int w = blockIdx.x, t = threadIdx.x;
    int g8 = w / 80, r = w - g8 * 80;
    int j = r >> 3, isp = g8 * 8 + (r & 7);   // same-isp j-group 8 apart -> same XCD
    int cch = isp / 12;
    int i0 = (isp - cch * 12) * 96;
    int k0 = isp * 96;
    if (t < 96) {
        float cv;
        if (it == 0) {
            cv = 0.1f;
        } else {
            int i = i0 + t;
            float bt_[OUT_NUM];
#pragma unroll
            for (int jp = 0; jp < OUT_NUM; ++jp) bt_[jp] = 0.f;
#pragma unroll 4
            for (int row = 0; row < 32; ++row) {
                const float2* p2 = reinterpret_cast<const float2*>(
                    &bp[(size_t)row * (IN_NUM * OUT_NUM) + i * OUT_NUM]);
#pragma unroll
                for (int q = 0; q < 5; ++q) {
                    float2 v = p2[q];
                    bt_[q * 2] += v.x; bt_[q * 2 + 1] += v.y;
                }
            }
            float m = -1e30f;
#pragma unroll
            for (int jp = 0; jp < OUT_NUM; ++jp) { bt_[jp] *= (1.f / NB); m = fmaxf(m, bt_[jp]); }
            float s = 0.f;
#pragma unroll
            for (int jp = 0; jp < OUT_NUM; ++jp) { bt_[jp] = __expf(bt_[jp] - m); s += bt_[jp]; }
            cv = bt_[j] / s;
        }
        ldc[t] = cv;
    }
    __syncthreads();
    const float* xp = xT + (size_t)k0 * NB + t;
    const float* wp = Wt2 + ((size_t)j * KTOT + k0) * OUT_DIM;   // block-uniform
    float acc[16];
#pragma unroll
    for (int d = 0; d < 16; ++d) acc[d] = 0.f;
#pragma unroll 4
    for (int kk = 0; kk < 96; ++kk) {
        float xv = xp[(size_t)kk * NB];
        float xs = xv * ldc[kk];
        const float* a = wp + kk * OUT_DIM;
#pragma unroll
        for (int d = 0; d < 16; ++d) acc[d] += a[d] * xs;
    }
    float* sp = spart + ((size_t)isp * OUT_NUM + j) * (OUT_DIM * NB) + t;
#pragma unroll
    for (int d = 0; d < 16; ++d) sp[d * NB] = acc[d];
}

// ---- p2: reduce spart over isp, squash, write dst[b][j][d] ----
__global__ __launch_bounds__(256, 4) void k_p2(const float* __restrict__ spart,
                                               float* __restrict__ dst) {
    __shared__ float smem[4672];
    float (*red)[32][17] = (float (*)[32][17])smem;
    float (*nrm)[9] = (float (*)[9])(smem + 4352);
    float* cf = smem + 4640;
    int wvar = blockIdx.x, t = threadIdx.x;
    int j = wvar >> 3, bt2 = wvar & 7;
    int ie = t >> 5, bb = t & 31;
    int b = bt2 * 32 + bb;
    float acc[16];
#pragma unroll
    for (int d = 0; d < 16; ++d) acc[d] = 0.f;
    for (int q = 0; q < 12; ++q) {
        int isp = ie * 12 + q;
        const float* sp = spart + (size_t)(isp * OUT_NUM + j) * (OUT_DIM * NB) + b;
#pragma unroll
        for (int d = 0; d < 16; ++d) acc[d] += sp[d * NB];
    }
#pragma unroll
    for (int d = 0; d < 16; ++d) red[ie][bb][d] = acc[d];
    __syncthreads();
    int bb2 = t >> 3, dp = t & 7;
    float s0 = 0.f, s1 = 0.f;
#pragma unroll
    for (int e = 0; e < 8; ++e) { s0 += red[e][bb2][dp * 2]; s1 += red[e][bb2][dp * 2 + 1]; }
    nrm[bb2][dp] = s0 * s0 + s1 * s1;
    __syncthreads();
    if (t < 32) {
        float qn = 0.f;
#pragma unroll
        for (int d = 0; d < 8; ++d) qn += nrm[t][d];
        cf[t] = qn / ((1.f + qn) * sqrtf(qn));
    }
    __syncthreads();
    float cs = cf[bb2];
    float* o = dst + (size_t)(bt2 * 32 + bb2) * (OUT_NUM * OUT_DIM) + j * OUT_DIM + dp * 2;
    o[0] = s0 * cs;
    o[1] = s1 * cs;
}

// ---- p3: bp[bq*8+c][i][j] = prev + sum_d Wt[j][d][k] * sum_{b in quarter} vt[b][j][d]*x[b][k] ----
// Body identical to R11/R13 (measured 14.2 us). ONLY the block-index decode changed:
// u = v*80 + j*8 + e; m = v*8 + e -> (kt,bq). The 10 j-blocks sharing one (kt,bq)
// x-slice differ only in j (stride 8) -> all on XCD e -> slice L2-resident, read once from LLC.
__global__ __launch_bounds__(256) void k_p3(const float* __restrict__ x,
                                            const float* __restrict__ vt,
                                            const float* __restrict__ Wt,
                                            float* __restrict__ bp, int it) {
    int u = blockIdx.x, t = threadIdx.x;
    int v = u / 80, r = u - v * 80;
    int j = r >> 3, e = r & 7;
    int m = v * 8 + e;               // 0..143
    int kt = m >> 2, bq = m & 3;     // 36 k-tiles x 4 b-quarters
    int k = kt * 256 + t;
    int c = k / IN_NUM, i = k - c * IN_NUM;
    const float* xk = x + k + (size_t)(bq * 64) * KTOT;
    const float* vjb = vt + (size_t)(bq * 64) * (OUT_NUM * OUT_DIM) + j * OUT_DIM;
    float macc[16];
#pragma unroll
    for (int d = 0; d < 16; ++d) macc[d] = 0.f;
#pragma unroll 8
    for (int b = 0; b < 64; ++b) {
        float xv = xk[(size_t)b * KTOT];
        const float* vb = vjb + (size_t)b * (OUT_NUM * OUT_DIM);   // block-uniform -> s_load
#pragma unroll
        for (int d = 0; d < 16; ++d) macc[d] += vb[d] * xv;
    }
    float bs = 0.f;
#pragma unroll
    for (int d = 0; d < 16; ++d)
        bs += macc[d] * Wt[(size_t)(j * OUT_DIM + d) * KTOT + k];
    size_t idx = (size_t)(bq * 8 + c) * (IN_NUM * OUT_NUM) + (size_t)i * OUT_NUM + j;
    float prev = (it == 0) ? 0.f : bp[idx];
    bp[idx] = prev + bs;
}

extern "C" void kernel_launch(void* const* d_in, const int* in_sizes, int n_in,
                              void* d_out, int out_size, void* d_ws, size_t ws_size,
                              hipStream_t stream) {
    const float* x = (const float*)d_in[0];   // [256][8][1152]
    const float* W = (const float*)d_in[1];   // [1152][10][16][8]
    float* out = (float*)d_out;               // [256][10][16][1]
    float* ws = (float*)d_ws;

    float* spart = ws + OFF_SPART;
    float* bp    = ws + OFF_BP;
    float* vt    = ws + OFF_VT;
    float* Wt    = ws + OFF_WT;
    float* Wt2   = ws + OFF_WT2;
    float* xT    = ws + OFF_XT;

    k_prep<<<dim3(936), dim3(256), 0, stream>>>(x, W, xT, Wt, Wt2);
    for (int it = 0; it < 3; ++it) {
        k_p1<<<dim3(960), dim3(256), 0, stream>>>(xT, Wt2, bp, spart, it);
        k_p2<<<dim3(80), dim3(256), 0, stream>>>(spart, it == 2 ? out : vt);
        if (it < 2) k_p3<<<dim3(1440), dim3(256), 0, stream>>>(x, vt, Wt, bp, it);
    }
}

// Round 16
// 121.040 us; speedup vs baseline: 4.1950x; 1.0196x over previous
//
#include <hip/hip_runtime.h>

#define IN_NUM 1152
#define OUT_NUM 10
#define OUT_DIM 16
#define IN_DIM 8
#define NB 256
#define KTOT 9216

// workspace float offsets
#define OFF_SPART 0
#define SZ_SPART (96 * OUT_NUM * OUT_DIM * NB)        // 3,932,160
#define OFF_BP (OFF_SPART + SZ_SPART)
#define SZ_BP (32 * IN_NUM * OUT_NUM)                 // 368,640
#define OFF_VT (OFF_BP + SZ_BP)
#define SZ_VT (NB * OUT_NUM * OUT_DIM)                // 40,960
#define OFF_WT (OFF_VT + SZ_VT)
#define SZ_WT (OUT_NUM * OUT_DIM * KTOT)              // Wt[j][d][k]
#define OFF_WT2 (OFF_WT + SZ_WT)
#define SZ_WT2 (OUT_NUM * KTOT * OUT_DIM)             // Wt2[j][k][d]

typedef short bf16x8 __attribute__((ext_vector_type(8)));
typedef float f32x4 __attribute__((ext_vector_type(4)));

__device__ __forceinline__ unsigned short f2bf(float f) {
    unsigned u = __float_as_uint(f);
    u = (u + 0x7FFFu + ((u >> 16) & 1u)) >> 16;   // round-to-nearest-even
    return (unsigned short)u;
}

// ---- prep: Wt[j][d*8+c][i], Wt2[j][c*1152+i][d] = W[i][j][d][c] (xT no longer needed) ----
__global__ __launch_bounds__(256) void k_prep(const float* __restrict__ W,
                                              float* __restrict__ Wt,
                                              float* __restrict__ Wt2) {
    __shared__ float lds2[32][129];
    int u = blockIdx.x, t = threadIdx.x;
    int itile = u / 10, j = u - itile * 10;
    int i0 = itile * 32;
    int r0 = t >> 5, c4b = t & 31;
#pragma unroll
    for (int rr = 0; rr < 4; ++rr) {
        int rrow = rr * 8 + r0;
        float4 w4 = *reinterpret_cast<const float4*>(
            &W[(size_t)(i0 + rrow) * 1280 + j * 128 + c4b * 4]);
        lds2[rrow][c4b * 4 + 0] = w4.x; lds2[rrow][c4b * 4 + 1] = w4.y;
        lds2[rrow][c4b * 4 + 2] = w4.z; lds2[rrow][c4b * 4 + 3] = w4.w;
    }
    __syncthreads();
    int ii = t & 31, dcq = t >> 5;
#pragma unroll
    for (int rr = 0; rr < 16; ++rr) {
        int dc = rr * 8 + dcq;
        Wt[(size_t)(j * 128 + dc) * IN_NUM + i0 + ii] = lds2[ii][dc];
    }
    int d4 = t & 3, ii2 = (t >> 2) & 31, ch0 = t >> 7;
#pragma unroll
    for (int c2 = 0; c2 < 4; ++c2) {
        int c = c2 * 2 + ch0;
        float4 o;
        o.x = lds2[ii2][(d4 * 4 + 0) * 8 + c];
        o.y = lds2[ii2][(d4 * 4 + 1) * 8 + c];
        o.z = lds2[ii2][(d4 * 4 + 2) * 8 + c];
        o.w = lds2[ii2][(d4 * 4 + 3) * 8 + c];
        *reinterpret_cast<float4*>(
            &Wt2[((size_t)j * KTOT + c * IN_NUM + i0 + ii2) * OUT_DIM + d4 * 4]) = o;
    }
}

// ---- p1 (MFMA): spart[isp][j][d][b] = sum_k (ldc[k]*W[k,d]) * x[b,k] ----
// Per block: S^T[256b x 16d] = x[256b x 96k] . atT^T[96k x 16d], 48 mfma_16x16x32_bf16.
// A-frag straight from global x (two float4/lane); B-frag from LDS atT (bf16, hoisted).
__global__ __launch_bounds__(256, 4) void k_p1(const float* __restrict__ x,
                                               const float* __restrict__ Wt2,
                                               const float* __restrict__ bp,
                                               float* __restrict__ spart, int it) {
    __shared__ float ldc[96];
    __shared__ unsigned short atT[16][100];   // bf16 A_w[d][k], pad 100 -> 2-way-free banks
    int w = blockIdx.x, t = threadIdx.x;
    int g8 = w / 80, r = w - g8 * 80;
    int j = r >> 3, isp = g8 * 8 + (r & 7);   // same-isp j-group 8 apart -> same XCD
    int cch = isp / 12;
    int i0 = (isp - cch * 12) * 96;
    int k0 = isp * 96;
    if (t < 96) {
        float cv;
        if (it == 0) {
            cv = 0.1f;
        } else {
            int i = i0 + t;
            float bt_[OUT_NUM];
#pragma unroll
            for (int jp = 0; jp < OUT_NUM; ++jp) bt_[jp] = 0.f;
#pragma unroll 4
            for (int row = 0; row < 32; ++row) {
                const float2* p2 = reinterpret_cast<const float2*>(
                    &bp[(size_t)row * (IN_NUM * OUT_NUM) + i * OUT_NUM]);
#pragma unroll
                for (int q = 0; q < 5; ++q) {
                    float2 v = p2[q];
                    bt_[q * 2] += v.x; bt_[q * 2 + 1] += v.y;
                }
            }
            float m = -1e30f;
#pragma unroll
            for (int jp = 0; jp < OUT_NUM; ++jp) { bt_[jp] *= (1.f / NB); m = fmaxf(m, bt_[jp]); }
            float s = 0.f;
#pragma unroll
            for (int jp = 0; jp < OUT_NUM; ++jp) { bt_[jp] = __expf(bt_[jp] - m); s += bt_[jp]; }
            cv = bt_[j] / s;
        }
        ldc[t] = cv;
    }
    __syncthreads();
    // build atT[d][kk] (coalesced Wt2 reads: d lane-minor)
    for (int e = t; e < 1536; e += 256) {
        int d = e & 15, kk = e >> 4;
        atT[d][kk] = f2bf(ldc[kk] * Wt2[((size_t)j * KTOT + k0 + kk) * OUT_DIM + d]);
    }
    __syncthreads();
    int lane = t & 63, wv = t >> 6;
    int lg = lane >> 4, lm = lane & 15;
    // B-frags, one per K-step, shared by all 4 b-tiles of this wave
    bf16x8 bfr[3];
#pragma unroll
    for (int ks = 0; ks < 3; ++ks) {
        const unsigned short* p0 = &atT[lm][ks * 32 + lg * 4];
        ushort4 u0 = *reinterpret_cast<const ushort4*>(p0);
        ushort4 u1 = *reinterpret_cast<const ushort4*>(p0 + 16);
        bfr[ks][0] = (short)u0.x; bfr[ks][1] = (short)u0.y;
        bfr[ks][2] = (short)u0.z; bfr[ks][3] = (short)u0.w;
        bfr[ks][4] = (short)u1.x; bfr[ks][5] = (short)u1.y;
        bfr[ks][6] = (short)u1.z; bfr[ks][7] = (short)u1.w;
    }
    float* sp = spart + ((size_t)isp * OUT_NUM + j) * (OUT_DIM * NB);
#pragma unroll
    for (int tb = 0; tb < 4; ++tb) {
        int tbase = (wv * 4 + tb) * 16;
        const float* xr = x + (size_t)(tbase + lm) * KTOT + k0 + lg * 4;
        f32x4 acc = {0.f, 0.f, 0.f, 0.f};
#pragma unroll
        for (int ks = 0; ks < 3; ++ks) {
            float4 a0 = *reinterpret_cast<const float4*>(xr + ks * 32);
            float4 a1 = *reinterpret_cast<const float4*>(xr + ks * 32 + 16);
            bf16x8 af;
            af[0] = (short)f2bf(a0.x); af[1] = (short)f2bf(a0.y);
            af[2] = (short)f2bf(a0.z); af[3] = (short)f2bf(a0.w);
            af[4] = (short)f2bf(a1.x); af[5] = (short)f2bf(a1.y);
            af[6] = (short)f2bf(a1.z); af[7] = (short)f2bf(a1.w);
            acc = __builtin_amdgcn_mfma_f32_16x16x32_bf16(af, bfr[ks], acc, 0, 0, 0);
        }
        // D row=(lg*4+reg)=b-in-tile, col=lm=d  ->  float4 store of 4 consecutive b
        *reinterpret_cast<float4*>(&sp[(size_t)lm * NB + tbase + lg * 4]) =
            make_float4(acc[0], acc[1], acc[2], acc[3]);
    }
}

// ---- p2: reduce spart over isp, squash, write dst[b][j][d] (R11 verbatim) ----
__global__ __launch_bounds__(256, 4) void k_p2(const float* __restrict__ spart,
                                               float* __restrict__ dst) {
    __shared__ float smem[4672];
    float (*red)[32][17] = (float (*)[32][17])smem;
    float (*nrm)[9] = (float (*)[9])(smem + 4352);
    float* cf = smem + 4640;
    int wvar = blockIdx.x, t = threadIdx.x;
    int j = wvar >> 3, bt2 = wvar & 7;
    int ie = t >> 5, bb = t & 31;
    int b = bt2 * 32 + bb;
    float acc[16];
#pragma unroll
    for (int d = 0; d < 16; ++d) acc[d] = 0.f;
    for (int q = 0; q < 12; ++q) {
        int isp = ie * 12 + q;
        const float* sp = spart + (size_t)(isp * OUT_NUM + j) * (OUT_DIM * NB) + b;
#pragma unroll
        for (int d = 0; d < 16; ++d) acc[d] += sp[d * NB];
    }
#pragma unroll
    for (int d = 0; d < 16; ++d) red[ie][bb][d] = acc[d];
    __syncthreads();
    int bb2 = t >> 3, dp = t & 7;
    float s0 = 0.f, s1 = 0.f;
#pragma unroll
    for (int e = 0; e < 8; ++e) { s0 += red[e][bb2][dp * 2]; s1 += red[e][bb2][dp * 2 + 1]; }
    nrm[bb2][dp] = s0 * s0 + s1 * s1;
    __syncthreads();
    if (t < 32) {
        float qn = 0.f;
#pragma unroll
        for (int d = 0; d < 8; ++d) qn += nrm[t][d];
        cf[t] = qn / ((1.f + qn) * sqrtf(qn));
    }
    __syncthreads();
    float cs = cf[bb2];
    float* o = dst + (size_t)(bt2 * 32 + bb2) * (OUT_NUM * OUT_DIM) + j * OUT_DIM + dp * 2;
    o[0] = s0 * cs;
    o[1] = s1 * cs;
}

// ---- p3: bp update (R11 verbatim — best measured config) ----
__global__ __launch_bounds__(256) void k_p3(const float* __restrict__ x,
                                            const float* __restrict__ vt,
                                            const float* __restrict__ Wt,
                                            float* __restrict__ bp, int it) {
    int u = blockIdx.x, t = threadIdx.x;
    int kt = u % 36;
    int jq = u / 36;
    int j = jq >> 2, bq = jq & 3;
    int k = kt * 256 + t;
    int c = k / IN_NUM, i = k - c * IN_NUM;
    const float* xk = x + k + (size_t)(bq * 64) * KTOT;
    const float* vjb = vt + (size_t)(bq * 64) * (OUT_NUM * OUT_DIM) + j * OUT_DIM;
    float macc[16];
#pragma unroll
    for (int d = 0; d < 16; ++d) macc[d] = 0.f;
#pragma unroll 8
    for (int b = 0; b < 64; ++b) {
        float xv = xk[(size_t)b * KTOT];
        const float* vb = vjb + (size_t)b * (OUT_NUM * OUT_DIM);   // block-uniform -> s_load
#pragma unroll
        for (int d = 0; d < 16; ++d) macc[d] += vb[d] * xv;
    }
    float bs = 0.f;
#pragma unroll
    for (int d = 0; d < 16; ++d)
        bs += macc[d] * Wt[(size_t)(j * OUT_DIM + d) * KTOT + k];
    size_t idx = (size_t)(bq * 8 + c) * (IN_NUM * OUT_NUM) + (size_t)i * OUT_NUM + j;
    float prev = (it == 0) ? 0.f : bp[idx];
    bp[idx] = prev + bs;
}

extern "C" void kernel_launch(void* const* d_in, const int* in_sizes, int n_in,
                              void* d_out, int out_size, void* d_ws, size_t ws_size,
                              hipStream_t stream) {
    const float* x = (const float*)d_in[0];   // [256][8][1152]
    const float* W = (const float*)d_in[1];   // [1152][10][16][8]
    float* out = (float*)d_out;               // [256][10][16][1]
    float* ws = (float*)d_ws;

    float* spart = ws + OFF_SPART;
    float* bp    = ws + OFF_BP;
    float* vt    = ws + OFF_VT;
    float* Wt    = ws + OFF_WT;
    float* Wt2   = ws + OFF_WT2;

    k_prep<<<dim3(360), dim3(256), 0, stream>>>(W, Wt, Wt2);
    for (int it = 0; it < 3; ++it) {
        k_p1<<<dim3(960), dim3(256), 0, stream>>>(x, Wt2, bp, spart, it);
        k_p2<<<dim3(80), dim3(256), 0, stream>>>(spart, it == 2 ? out : vt);
        if (it < 2) k_p3<<<dim3(1440), dim3(256), 0, stream>>>(x, vt, Wt, bp, it);
    }
}